// Round 1
// baseline (934.081 us; speedup 1.0000x reference)
//
#include <hip/hip_runtime.h>
#include <cstdint>
#include <cstddef>

// Problem constants (B=2, H=16, S=2048, D=128), fp32 in/out.
#define BH_N 32
#define S_N 2048
#define D_N 128
#define QT 64        // Q rows per block
#define KT 64        // K rows per tile
#define LDQ 136      // LDS stride for Qs/Ks (bf16 elems): 272B, 16B-aligned, 68 words == 4 mod 32
#define LDV 72       // LDS stride for Vt: 144B, 16B-aligned, 36 words == 4 mod 32
#define LDW 72       // LDS stride for Ws

typedef short bf16x8 __attribute__((ext_vector_type(8)));
typedef float f32x4  __attribute__((ext_vector_type(4)));

__device__ __forceinline__ unsigned short f2bf(float f) {
    union { float f; unsigned u; } v; v.f = f;
    unsigned r = v.u + 0x7fffu + ((v.u >> 16) & 1u);   // round-to-nearest-even
    return (unsigned short)(r >> 16);
}

__global__ __launch_bounds__(256, 2)
void attn_fused_kernel(const float* __restrict__ Q, const float* __restrict__ K,
                       const float* __restrict__ V, float* __restrict__ OutO,
                       float* __restrict__ OutW)
{
    __shared__ __align__(16) unsigned short Qs[QT][LDQ];
    __shared__ __align__(16) unsigned short Ks[KT][LDQ];
    __shared__ __align__(16) unsigned short Vt[D_N][LDV];   // Vt[d][k] = V[k][d]
    __shared__ __align__(16) unsigned short Ws[QT][LDW];

    const int t    = threadIdx.x;
    const int bh   = blockIdx.y;
    const int q0   = blockIdx.x * QT;
    const int lane = t & 63;
    const int wave = t >> 6;
    const int quad = lane >> 4;
    const int l15  = lane & 15;
    const int wm   = wave * 16;          // wave's 16-row strip within the 64-row Q tile

    const float scale = 0.08838834764831845f;  // 1/sqrt(128)

    const size_t head_base = (size_t)bh * S_N * D_N;
    const float* Qp = Q + head_base + (size_t)q0 * D_N;
    const float* Kp = K + head_base;
    const float* Vp = V + head_base;

    // ---- stage Q tile (64 x 128 fp32 -> bf16) ----
    #pragma unroll
    for (int r = 0; r < 8; ++r) {
        int idx = r * 256 + t;           // 0..2047 float4 slots
        int row = idx >> 5;              // 32 float4 per row
        int c4  = (idx & 31) << 2;
        const float4 v = *(const float4*)(Qp + (size_t)row * D_N + c4);
        Qs[row][c4 + 0] = f2bf(v.x);
        Qs[row][c4 + 1] = f2bf(v.y);
        Qs[row][c4 + 2] = f2bf(v.z);
        Qs[row][c4 + 3] = f2bf(v.w);
    }

    // Online-softmax state: each lane tracks 4 rows (quad*4+r), replicated across the 16 lanes of its quad.
    float m_run[4], l_run[4];
    #pragma unroll
    for (int r = 0; r < 4; ++r) { m_run[r] = -1e30f; l_run[r] = 0.0f; }

    // ================= PASS 1: row max + expsum (no S materialization) =================
    for (int kt = 0; kt < S_N / KT; ++kt) {
        __syncthreads();
        #pragma unroll
        for (int r = 0; r < 8; ++r) {
            int idx = r * 256 + t;
            int row = idx >> 5;
            int c4  = (idx & 31) << 2;
            const float4 v = *(const float4*)(Kp + (size_t)(kt * KT + row) * D_N + c4);
            Ks[row][c4 + 0] = f2bf(v.x);
            Ks[row][c4 + 1] = f2bf(v.y);
            Ks[row][c4 + 2] = f2bf(v.z);
            Ks[row][c4 + 3] = f2bf(v.w);
        }
        __syncthreads();

        f32x4 acc[4];
        #pragma unroll
        for (int nt = 0; nt < 4; ++nt) acc[nt] = (f32x4){0.f, 0.f, 0.f, 0.f};
        #pragma unroll
        for (int dc = 0; dc < 4; ++dc) {
            bf16x8 a = *(const bf16x8*)&Qs[wm + l15][dc * 32 + quad * 8];
            #pragma unroll
            for (int nt = 0; nt < 4; ++nt) {
                bf16x8 b = *(const bf16x8*)&Ks[nt * 16 + l15][dc * 32 + quad * 8];
                acc[nt] = __builtin_amdgcn_mfma_f32_16x16x32_bf16(a, b, acc[nt], 0, 0, 0);
            }
        }
        #pragma unroll
        for (int r = 0; r < 4; ++r) {
            float s0 = acc[0][r] * scale, s1 = acc[1][r] * scale;
            float s2 = acc[2][r] * scale, s3 = acc[3][r] * scale;
            float mx = fmaxf(fmaxf(s0, s1), fmaxf(s2, s3));
            #pragma unroll
            for (int msk = 1; msk < 16; msk <<= 1) mx = fmaxf(mx, __shfl_xor(mx, msk));
            float m_new = fmaxf(m_run[r], mx);
            float p = __expf(s0 - m_new) + __expf(s1 - m_new) +
                      __expf(s2 - m_new) + __expf(s3 - m_new);
            #pragma unroll
            for (int msk = 1; msk < 16; msk <<= 1) p += __shfl_xor(p, msk);
            l_run[r] = l_run[r] * __expf(m_run[r] - m_new) + p;
            m_run[r] = m_new;
        }
    }

    float inv_l[4];
    #pragma unroll
    for (int r = 0; r < 4; ++r) inv_l[r] = 1.0f / l_run[r];

    f32x4 oacc[8];
    #pragma unroll
    for (int dt = 0; dt < 8; ++dt) oacc[dt] = (f32x4){0.f, 0.f, 0.f, 0.f};

    float* Wrow = OutW + (size_t)bh * S_N * S_N + (size_t)q0 * S_N;

    // ================= PASS 2: recompute S, write weights, accumulate O = P*V =================
    for (int kt = 0; kt < S_N / KT; ++kt) {
        __syncthreads();
        #pragma unroll
        for (int r = 0; r < 8; ++r) {
            int idx = r * 256 + t;
            int row = idx >> 5;
            int c4  = (idx & 31) << 2;
            const float4 v = *(const float4*)(Kp + (size_t)(kt * KT + row) * D_N + c4);
            Ks[row][c4 + 0] = f2bf(v.x);
            Ks[row][c4 + 1] = f2bf(v.y);
            Ks[row][c4 + 2] = f2bf(v.z);
            Ks[row][c4 + 3] = f2bf(v.w);
        }
        // stage V tile transposed: Vt[d][k]
        {
            int d  = t & 127;
            int kh = t >> 7;             // 0..1
            #pragma unroll
            for (int g = 0; g < 8; ++g) {
                int kl = (kh * 8 + g) * 4;   // 0,4,...,60
                union { unsigned short u[4]; uint2 v2; } pk;
                #pragma unroll
                for (int i = 0; i < 4; ++i)
                    pk.u[i] = f2bf(Vp[(size_t)(kt * KT + kl + i) * D_N + d]);
                *(uint2*)&Vt[d][kl] = pk.v2;
            }
        }
        __syncthreads();

        f32x4 acc[4];
        #pragma unroll
        for (int nt = 0; nt < 4; ++nt) acc[nt] = (f32x4){0.f, 0.f, 0.f, 0.f};
        #pragma unroll
        for (int dc = 0; dc < 4; ++dc) {
            bf16x8 a = *(const bf16x8*)&Qs[wm + l15][dc * 32 + quad * 8];
            #pragma unroll
            for (int nt = 0; nt < 4; ++nt) {
                bf16x8 b = *(const bf16x8*)&Ks[nt * 16 + l15][dc * 32 + quad * 8];
                acc[nt] = __builtin_amdgcn_mfma_f32_16x16x32_bf16(a, b, acc[nt], 0, 0, 0);
            }
        }

        // normalize, write weights (fp32 global) and Ws (bf16 LDS, A-operand layout)
        #pragma unroll
        for (int nt = 0; nt < 4; ++nt) {
            #pragma unroll
            for (int r = 0; r < 4; ++r) {
                float w = __expf(acc[nt][r] * scale - m_run[r]) * inv_l[r];
                int row = wm + quad * 4 + r;
                int col = kt * KT + nt * 16 + l15;
                Wrow[(size_t)row * S_N + col] = w;
                Ws[row][nt * 16 + l15] = f2bf(w);
            }
        }

        // O += W * V   (per-wave rows; Ws rows are wave-private, within-wave LDS RAW handled by waitcnt)
        #pragma unroll
        for (int kc = 0; kc < 2; ++kc) {
            bf16x8 a = *(const bf16x8*)&Ws[wm + l15][kc * 32 + quad * 8];
            #pragma unroll
            for (int dt = 0; dt < 8; ++dt) {
                bf16x8 b = *(const bf16x8*)&Vt[dt * 16 + l15][kc * 32 + quad * 8];
                oacc[dt] = __builtin_amdgcn_mfma_f32_16x16x32_bf16(a, b, oacc[dt], 0, 0, 0);
            }
        }
    }

    // ---- write O tile ----
    float* Orow = OutO + head_base + (size_t)q0 * D_N;
    #pragma unroll
    for (int dt = 0; dt < 8; ++dt) {
        #pragma unroll
        for (int r = 0; r < 4; ++r) {
            int row = wm + quad * 4 + r;
            Orow[(size_t)row * D_N + dt * 16 + l15] = oacc[dt][r];
        }
    }
}

extern "C" void kernel_launch(void* const* d_in, const int* in_sizes, int n_in,
                              void* d_out, int out_size, void* d_ws, size_t ws_size,
                              hipStream_t stream) {
    const float* Q = (const float*)d_in[0];
    const float* K = (const float*)d_in[1];
    const float* V = (const float*)d_in[2];
    float* OutO = (float*)d_out;                                  // [B,H,S,D] = 8388608 floats
    float* OutW = OutO + (size_t)BH_N * S_N * D_N;                // [B,H,S,S] = 134217728 floats

    dim3 grid(S_N / QT, BH_N);   // (32 q-tiles, 32 heads)
    dim3 block(256);
    attn_fused_kernel<<<grid, block, 0, stream>>>(Q, K, V, OutO, OutW);
}